// Round 6
// baseline (78.796 us; speedup 1.0000x reference)
//
#include <hip/hip_runtime.h>
#include <hip/hip_bf16.h>

// DistanceProbe via bf16 MFMA (3 kernels; cooperative single-kernel failed under
// the harness's launch/capture path in R5 — reverted):
//   T = batch@proj  (M=4096, K=1024, N=128), stored bf16 fragment-major
//   D[b,i,j] = n_i + n_j - 2*(T T^T)[b,i,j], norms from bf16-rounded T
//
// Kernel 0: proj fp32 [1024][128] -> g_projB bf16 frag-major [k/8][n][k&7]
// Kernel 1: GEMM (MFMA 16x16x32 bf16). BM=16, BN=64 (half), BK=128, 512 blocks
//           (2/CU). R6: ALL 8 iterations of A prefetched upfront (16 float4,
//           64 VGPR) -> the 8 per-barrier A-latency exposures collapse to one
//           burst; per-iter barrier waits only on L2-hot B + LDS.
// Kernel 2: Gram + distance epilogue, fragments straight from L2.

#define S_DIM 512
#define K_DIM 1024
#define R_DIM 128
#define M_ROWS 4096  // 8*512

typedef __attribute__((ext_vector_type(8))) short short8;
typedef __attribute__((ext_vector_type(4))) float float4v;

__device__ unsigned short g_projB[(K_DIM / 8) * R_DIM * 8];   // [q][n][j], 256 KB
__device__ unsigned short g_Tf[8 * (R_DIM / 8) * S_DIM * 8];  // [b][n/8][row][j], 1 MB
__device__ float g_normsP[2][M_ROWS];                         // per-half partial norms

__device__ __forceinline__ unsigned short f2b(float f) {
  unsigned int u = __builtin_bit_cast(unsigned int, f);
  u += 0x7FFFu + ((u >> 16) & 1u);  // RNE
  return (unsigned short)(u >> 16);
}
__device__ __forceinline__ float b2f(unsigned short b) {
  unsigned int u = ((unsigned int)b) << 16;
  return __builtin_bit_cast(float, u);
}

// ---------------- Kernel 0: proj -> bf16 frag-major ----------------
// grid 128 x 256 thr: k = bid*8 + t>>5 (full 1024), n4 = (t&31)*4 (full 128).
__global__ __launch_bounds__(256) void prep_proj(const float* __restrict__ proj) {
  const int t = threadIdx.x;
  const int k = blockIdx.x * 8 + (t >> 5);
  const int n4 = (t & 31) * 4;
  const float4 v = *(const float4*)(proj + (size_t)k * R_DIM + n4);
  const unsigned short b0 = f2b(v.x), b1 = f2b(v.y), b2 = f2b(v.z), b3 = f2b(v.w);
  const int q = k >> 3, j = k & 7;
  g_projB[((size_t)q * R_DIM + n4 + 0) * 8 + j] = b0;
  g_projB[((size_t)q * R_DIM + n4 + 1) * 8 + j] = b1;
  g_projB[((size_t)q * R_DIM + n4 + 2) * 8 + j] = b2;
  g_projB[((size_t)q * R_DIM + n4 + 3) * 8 + j] = b3;
}

// ---------------- Kernel 1: T = batch@proj (MFMA) + partial norms ----------------
// 256 threads = 4 waves; wave w owns n-subtile n0 = 16w within this block's 64-col half.
// BK=128 -> 8 c-iterations, 4 MFMAs/wave/iter. A fully prefetched; B 1-deep
// register prefetch; double-buffered LDS, single barrier per iteration.
__global__ __launch_bounds__(256) void transform_kernel(const float* __restrict__ batch) {
  // A: chunk index = q*16 + m  (16 q-units x 16 m x 8 bf16) = 4 KB/buf
  // B: chunk index = q*64 + n  (16 q-units x 64 n x 8 bf16) = 16 KB/buf
  // Staging writes and frag reads are contiguous-16B-chunk patterns
  // (<=2-way bank aliasing -> free, m136).
  __shared__ __attribute__((aligned(16))) unsigned short As[2][16 * 16 * 8];
  __shared__ __attribute__((aligned(16))) unsigned short Bs[2][16 * 64 * 8];
  __shared__ float sh_norm[16];

  const int t = threadIdx.x;
  if (t < 16) sh_norm[t] = 0.0f;
  const int half = blockIdx.x;        // 0/1 -> n columns [0,64) / [64,128)
  const int M0 = blockIdx.y * 16;
  const int nb64 = half * 64;
  const int lane = t & 63;
  const int wave = t >> 6;
  const int quad = lane >> 4;
  const int l16 = lane & 15;
  const int n0 = wave * 16;

  // A staging: thread t -> (q = t>>4, m = t&15); 8 fp32 (32 B) at k = c*128 + q*8.
  const int aq = t >> 4;
  const int am = t & 15;
  const float* aptr = batch + (size_t)(M0 + am) * K_DIM + aq * 8;
  // B staging: thread t -> n = t&63, q = wave*4 + s.
  const unsigned short* bptr =
      g_projB + ((size_t)(wave * 4) * R_DIM + nb64 + (t & 63)) * 8;

  // ---- R6: prefetch ALL A (8 iters x 32 B) in one burst ----
  float4 aReg[8][2];
#pragma unroll
  for (int c = 0; c < 8; c++) {
    aReg[c][0] = *(const float4*)(aptr + c * 128);
    aReg[c][1] = *(const float4*)(aptr + c * 128 + 4);
  }

  uint4 bv0 = *(const uint4*)(bptr);
  uint4 bv1 = *(const uint4*)(bptr + R_DIM * 8);
  uint4 bv2 = *(const uint4*)(bptr + 2 * R_DIM * 8);
  uint4 bv3 = *(const uint4*)(bptr + 3 * R_DIM * 8);

  float4v acc = {0.f, 0.f, 0.f, 0.f};

  for (int c = 0; c < 8; c++) {
    const int buf = c & 1;
    // pack 8 fp32 -> 8 bf16 -> one b128 LDS store
    uint4 ap;
    ap.x = (unsigned int)f2b(aReg[c][0].x) | ((unsigned int)f2b(aReg[c][0].y) << 16);
    ap.y = (unsigned int)f2b(aReg[c][0].z) | ((unsigned int)f2b(aReg[c][0].w) << 16);
    ap.z = (unsigned int)f2b(aReg[c][1].x) | ((unsigned int)f2b(aReg[c][1].y) << 16);
    ap.w = (unsigned int)f2b(aReg[c][1].z) | ((unsigned int)f2b(aReg[c][1].w) << 16);
    *(uint4*)(&As[buf][(size_t)t * 8]) = ap;  // chunk aq*16+am == t
    *(uint4*)(&Bs[buf][((size_t)(wave * 4 + 0) * 64 + (t & 63)) * 8]) = bv0;
    *(uint4*)(&Bs[buf][((size_t)(wave * 4 + 1) * 64 + (t & 63)) * 8]) = bv1;
    *(uint4*)(&Bs[buf][((size_t)(wave * 4 + 2) * 64 + (t & 63)) * 8]) = bv2;
    *(uint4*)(&Bs[buf][((size_t)(wave * 4 + 3) * 64 + (t & 63)) * 8]) = bv3;
    __syncthreads();
    if (c < 7) {
      const unsigned short* bp = bptr + (size_t)(c + 1) * 16 * R_DIM * 8;
      bv0 = *(const uint4*)(bp);
      bv1 = *(const uint4*)(bp + R_DIM * 8);
      bv2 = *(const uint4*)(bp + 2 * R_DIM * 8);
      bv3 = *(const uint4*)(bp + 3 * R_DIM * 8);
    }
#pragma unroll
    for (int ks = 0; ks < 4; ks++) {
      const int q = ks * 4 + quad;
      const short8 af = *(const short8*)(&As[buf][((size_t)q * 16 + l16) * 8]);
      const short8 bf = *(const short8*)(&Bs[buf][((size_t)q * 64 + n0 + l16) * 8]);
      acc = __builtin_amdgcn_mfma_f32_16x16x32_bf16(af, bf, acc, 0, 0, 0);
    }
    // single barrier/iter: store_{c+1} goes to buf^1, protected by barrier_c.
  }

  // Epilogue: lane holds T[M0 + quad*4 + r][nb64 + n0 + l16] in acc[r].
  const int n = nb64 + n0 + l16;
  float sq[4];
#pragma unroll
  for (int r = 0; r < 4; r++) {
    const unsigned short tb = f2b(acc[r]);
    const float tv = b2f(tb);
    sq[r] = tv * tv;
    const int gm = M0 + quad * 4 + r;
    const int bidx = gm >> 9, row = gm & 511;
    g_Tf[(((size_t)bidx * 16 + (n >> 3)) * S_DIM + row) * 8 + (n & 7)] = tb;
  }
#pragma unroll
  for (int r = 0; r < 4; r++) {
    float v = sq[r];
    v += __shfl_xor(v, 1);
    v += __shfl_xor(v, 2);
    v += __shfl_xor(v, 4);
    v += __shfl_xor(v, 8);
    if (l16 == 0) atomicAdd(&sh_norm[quad * 4 + r], v);
  }
  __syncthreads();
  if (t < 16) g_normsP[half][M0 + t] = sh_norm[t];
}

// ---------------- Kernel 2: D = n_i + n_j - 2 * T T^T ----------------
// grid (8 jt, 8 it, 8 b), 256 thr = 4 waves; wave w: rows i0+16w x 64 cols.
__global__ __launch_bounds__(256) void dist_kernel(float* __restrict__ out) {
  const int t = threadIdx.x;
  const int lane = t & 63;
  const int wave = t >> 6;
  const int quad = lane >> 4;
  const int l16 = lane & 15;
  const int b = blockIdx.z;
  const int i0 = blockIdx.y * 64 + wave * 16;
  const int j0 = blockIdx.x * 64;

  const unsigned short* Tb = g_Tf + (size_t)b * 16 * S_DIM * 8;

  short8 af[4];
#pragma unroll
  for (int ks = 0; ks < 4; ks++) {
    const int q64 = ks * 4 + quad;
    af[ks] = *(const short8*)(Tb + ((size_t)q64 * S_DIM + i0 + l16) * 8);
  }
  short8 bfr[4][4];
#pragma unroll
  for (int jt = 0; jt < 4; jt++)
#pragma unroll
    for (int ks = 0; ks < 4; ks++) {
      const int q64 = ks * 4 + quad;
      bfr[jt][ks] = *(const short8*)(Tb + ((size_t)q64 * S_DIM + j0 + jt * 16 + l16) * 8);
    }

  float4v acc[4];
#pragma unroll
  for (int jt = 0; jt < 4; jt++) acc[jt] = (float4v){0.f, 0.f, 0.f, 0.f};
#pragma unroll
  for (int jt = 0; jt < 4; jt++)
#pragma unroll
    for (int ks = 0; ks < 4; ks++)
      acc[jt] = __builtin_amdgcn_mfma_f32_16x16x32_bf16(af[ks], bfr[jt][ks], acc[jt], 0, 0, 0);

  const float* np0 = g_normsP[0] + (size_t)b * S_DIM;
  const float* np1 = g_normsP[1] + (size_t)b * S_DIM;
  float ni[4];
#pragma unroll
  for (int r = 0; r < 4; r++) {
    const int i = i0 + quad * 4 + r;
    ni[r] = np0[i] + np1[i];
  }

  float* ob = out + (size_t)b * S_DIM * S_DIM;
#pragma unroll
  for (int jt = 0; jt < 4; jt++) {
    const int j = j0 + jt * 16 + l16;
    const float nj = np0[j] + np1[j];
#pragma unroll
    for (int r = 0; r < 4; r++) {
      const int i = i0 + quad * 4 + r;
      ob[(size_t)i * S_DIM + j] = ni[r] + nj - 2.0f * acc[jt][r];
    }
  }
}

extern "C" void kernel_launch(void* const* d_in, const int* in_sizes, int n_in,
                              void* d_out, int out_size, void* d_ws, size_t ws_size,
                              hipStream_t stream) {
  const float* batch = (const float*)d_in[0];
  const float* proj = (const float*)d_in[1];
  float* out = (float*)d_out;
  hipLaunchKernelGGL(prep_proj, dim3(128), dim3(256), 0, stream, proj);
  hipLaunchKernelGGL(transform_kernel, dim3(2, 256), dim3(256), 0, stream, batch);
  hipLaunchKernelGGL(dist_kernel, dim3(8, 8, 8), dim3(256), 0, stream, out);
}

// Round 7
// 76.310 us; speedup vs baseline: 1.0326x; 1.0326x over previous
//
#include <hip/hip_runtime.h>
#include <hip/hip_bf16.h>

// DistanceProbe via bf16 MFMA (R4 configuration — measured best, 76.6 us).
//   T = batch@proj  (M=4096, K=1024, N=128), stored bf16 fragment-major
//   D[b,i,j] = n_i + n_j - 2*(T T^T)[b,i,j], norms from bf16-rounded T
//
// Kernel 0: proj fp32 [1024][128] -> g_projB bf16 frag-major [k/8][n][k&7]
// Kernel 1: GEMM (MFMA 16x16x32 bf16). BM=16, BN=64 (half), BK=128.
//           512 blocks (2/CU): two blocks' barrier stalls overlap (m114).
//           1-deep register prefetch, double-buffered LDS, 1 barrier/iter.
//           (R6's full-A-prefetch variant regressed ~2 us — reverted.)
// Kernel 2: Gram + distance epilogue, fragments straight from L2.
//
// Session note: timed region carries ~64 us harness floor (256 MiB d_ws
// poison-fill at ~78% HBM peak + d_in restore + fills + dispatch ramps);
// kernels themselves are ~12 us vs ~8 us structural ideal.

#define S_DIM 512
#define K_DIM 1024
#define R_DIM 128
#define M_ROWS 4096  // 8*512

typedef __attribute__((ext_vector_type(8))) short short8;
typedef __attribute__((ext_vector_type(4))) float float4v;

__device__ unsigned short g_projB[(K_DIM / 8) * R_DIM * 8];   // [q][n][j], 256 KB
__device__ unsigned short g_Tf[8 * (R_DIM / 8) * S_DIM * 8];  // [b][n/8][row][j], 1 MB
__device__ float g_normsP[2][M_ROWS];                         // per-half partial norms

__device__ __forceinline__ unsigned short f2b(float f) {
  unsigned int u = __builtin_bit_cast(unsigned int, f);
  u += 0x7FFFu + ((u >> 16) & 1u);  // RNE
  return (unsigned short)(u >> 16);
}
__device__ __forceinline__ float b2f(unsigned short b) {
  unsigned int u = ((unsigned int)b) << 16;
  return __builtin_bit_cast(float, u);
}

// ---------------- Kernel 0: proj -> bf16 frag-major ----------------
// grid 128 x 256 thr: k = bid*8 + t>>5 (full 1024), n4 = (t&31)*4 (full 128).
__global__ __launch_bounds__(256) void prep_proj(const float* __restrict__ proj) {
  const int t = threadIdx.x;
  const int k = blockIdx.x * 8 + (t >> 5);
  const int n4 = (t & 31) * 4;
  const float4 v = *(const float4*)(proj + (size_t)k * R_DIM + n4);
  const unsigned short b0 = f2b(v.x), b1 = f2b(v.y), b2 = f2b(v.z), b3 = f2b(v.w);
  const int q = k >> 3, j = k & 7;
  g_projB[((size_t)q * R_DIM + n4 + 0) * 8 + j] = b0;
  g_projB[((size_t)q * R_DIM + n4 + 1) * 8 + j] = b1;
  g_projB[((size_t)q * R_DIM + n4 + 2) * 8 + j] = b2;
  g_projB[((size_t)q * R_DIM + n4 + 3) * 8 + j] = b3;
}

// ---------------- Kernel 1: T = batch@proj (MFMA) + partial norms ----------------
// 256 threads = 4 waves; wave w owns n-subtile n0 = 16w within this block's 64-col half.
// BK=128 -> 8 c-iterations, 4 MFMAs/wave/iter. Register-prefetch double-buffered LDS,
// single barrier per iteration (store_{c+1} to buf^1 only after barrier_c).
__global__ __launch_bounds__(256) void transform_kernel(const float* __restrict__ batch) {
  // A: chunk index = q*16 + m  (16 q-units x 16 m x 8 bf16) = 4 KB/buf
  // B: chunk index = q*64 + n  (16 q-units x 64 n x 8 bf16) = 16 KB/buf
  // Staging writes and frag reads are contiguous-16B-chunk patterns
  // (<=2-way bank aliasing -> free, m136).
  __shared__ __attribute__((aligned(16))) unsigned short As[2][16 * 16 * 8];
  __shared__ __attribute__((aligned(16))) unsigned short Bs[2][16 * 64 * 8];
  __shared__ float sh_norm[16];

  const int t = threadIdx.x;
  if (t < 16) sh_norm[t] = 0.0f;
  const int half = blockIdx.x;        // 0/1 -> n columns [0,64) / [64,128)
  const int M0 = blockIdx.y * 16;
  const int nb64 = half * 64;
  const int lane = t & 63;
  const int wave = t >> 6;
  const int quad = lane >> 4;
  const int l16 = lane & 15;
  const int n0 = wave * 16;

  // A staging: thread t -> (q = t>>4, m = t&15); 8 fp32 (32 B) at k = c*128 + q*8.
  const int aq = t >> 4;
  const int am = t & 15;
  const float* aptr = batch + (size_t)(M0 + am) * K_DIM + aq * 8;
  // B staging: thread t -> n = t&63, q = wave*4 + s.
  const unsigned short* bptr =
      g_projB + ((size_t)(wave * 4) * R_DIM + nb64 + (t & 63)) * 8;

  float4 a0 = *(const float4*)(aptr);
  float4 a1 = *(const float4*)(aptr + 4);
  uint4 bv0 = *(const uint4*)(bptr);
  uint4 bv1 = *(const uint4*)(bptr + R_DIM * 8);
  uint4 bv2 = *(const uint4*)(bptr + 2 * R_DIM * 8);
  uint4 bv3 = *(const uint4*)(bptr + 3 * R_DIM * 8);

  float4v acc = {0.f, 0.f, 0.f, 0.f};

  for (int c = 0; c < 8; c++) {
    const int buf = c & 1;
    // pack 8 fp32 -> 8 bf16 -> one b128 LDS store
    uint4 ap;
    ap.x = (unsigned int)f2b(a0.x) | ((unsigned int)f2b(a0.y) << 16);
    ap.y = (unsigned int)f2b(a0.z) | ((unsigned int)f2b(a0.w) << 16);
    ap.z = (unsigned int)f2b(a1.x) | ((unsigned int)f2b(a1.y) << 16);
    ap.w = (unsigned int)f2b(a1.z) | ((unsigned int)f2b(a1.w) << 16);
    *(uint4*)(&As[buf][(size_t)t * 8]) = ap;  // chunk aq*16+am == t
    *(uint4*)(&Bs[buf][((size_t)(wave * 4 + 0) * 64 + (t & 63)) * 8]) = bv0;
    *(uint4*)(&Bs[buf][((size_t)(wave * 4 + 1) * 64 + (t & 63)) * 8]) = bv1;
    *(uint4*)(&Bs[buf][((size_t)(wave * 4 + 2) * 64 + (t & 63)) * 8]) = bv2;
    *(uint4*)(&Bs[buf][((size_t)(wave * 4 + 3) * 64 + (t & 63)) * 8]) = bv3;
    __syncthreads();
    if (c < 7) {
      a0 = *(const float4*)(aptr + (c + 1) * 128);
      a1 = *(const float4*)(aptr + (c + 1) * 128 + 4);
      const unsigned short* bp = bptr + (size_t)(c + 1) * 16 * R_DIM * 8;
      bv0 = *(const uint4*)(bp);
      bv1 = *(const uint4*)(bp + R_DIM * 8);
      bv2 = *(const uint4*)(bp + 2 * R_DIM * 8);
      bv3 = *(const uint4*)(bp + 3 * R_DIM * 8);
    }
#pragma unroll
    for (int ks = 0; ks < 4; ks++) {
      const int q = ks * 4 + quad;
      const short8 af = *(const short8*)(&As[buf][((size_t)q * 16 + l16) * 8]);
      const short8 bf = *(const short8*)(&Bs[buf][((size_t)q * 64 + n0 + l16) * 8]);
      acc = __builtin_amdgcn_mfma_f32_16x16x32_bf16(af, bf, acc, 0, 0, 0);
    }
  }

  // Epilogue: lane holds T[M0 + quad*4 + r][nb64 + n0 + l16] in acc[r].
  const int n = nb64 + n0 + l16;
  float sq[4];
#pragma unroll
  for (int r = 0; r < 4; r++) {
    const unsigned short tb = f2b(acc[r]);
    const float tv = b2f(tb);
    sq[r] = tv * tv;
    const int gm = M0 + quad * 4 + r;
    const int bidx = gm >> 9, row = gm & 511;
    g_Tf[(((size_t)bidx * 16 + (n >> 3)) * S_DIM + row) * 8 + (n & 7)] = tb;
  }
#pragma unroll
  for (int r = 0; r < 4; r++) {
    float v = sq[r];
    v += __shfl_xor(v, 1);
    v += __shfl_xor(v, 2);
    v += __shfl_xor(v, 4);
    v += __shfl_xor(v, 8);
    if (l16 == 0) atomicAdd(&sh_norm[quad * 4 + r], v);
  }
  __syncthreads();
  if (t < 16) g_normsP[half][M0 + t] = sh_norm[t];
}

// ---------------- Kernel 2: D = n_i + n_j - 2 * T T^T ----------------
// grid (8 jt, 8 it, 8 b), 256 thr = 4 waves; wave w: rows i0+16w x 64 cols.
__global__ __launch_bounds__(256) void dist_kernel(float* __restrict__ out) {
  const int t = threadIdx.x;
  const int lane = t & 63;
  const int wave = t >> 6;
  const int quad = lane >> 4;
  const int l16 = lane & 15;
  const int b = blockIdx.z;
  const int i0 = blockIdx.y * 64 + wave * 16;
  const int j0 = blockIdx.x * 64;

  const unsigned short* Tb = g_Tf + (size_t)b * 16 * S_DIM * 8;

  short8 af[4];
#pragma unroll
  for (int ks = 0; ks < 4; ks++) {
    const int q64 = ks * 4 + quad;
    af[ks] = *(const short8*)(Tb + ((size_t)q64 * S_DIM + i0 + l16) * 8);
  }
  short8 bfr[4][4];
#pragma unroll
  for (int jt = 0; jt < 4; jt++)
#pragma unroll
    for (int ks = 0; ks < 4; ks++) {
      const int q64 = ks * 4 + quad;
      bfr[jt][ks] = *(const short8*)(Tb + ((size_t)q64 * S_DIM + j0 + jt * 16 + l16) * 8);
    }

  float4v acc[4];
#pragma unroll
  for (int jt = 0; jt < 4; jt++) acc[jt] = (float4v){0.f, 0.f, 0.f, 0.f};
#pragma unroll
  for (int jt = 0; jt < 4; jt++)
#pragma unroll
    for (int ks = 0; ks < 4; ks++)
      acc[jt] = __builtin_amdgcn_mfma_f32_16x16x32_bf16(af[ks], bfr[jt][ks], acc[jt], 0, 0, 0);

  const float* np0 = g_normsP[0] + (size_t)b * S_DIM;
  const float* np1 = g_normsP[1] + (size_t)b * S_DIM;
  float ni[4];
#pragma unroll
  for (int r = 0; r < 4; r++) {
    const int i = i0 + quad * 4 + r;
    ni[r] = np0[i] + np1[i];
  }

  float* ob = out + (size_t)b * S_DIM * S_DIM;
#pragma unroll
  for (int jt = 0; jt < 4; jt++) {
    const int j = j0 + jt * 16 + l16;
    const float nj = np0[j] + np1[j];
#pragma unroll
    for (int r = 0; r < 4; r++) {
      const int i = i0 + quad * 4 + r;
      ob[(size_t)i * S_DIM + j] = ni[r] + nj - 2.0f * acc[jt][r];
    }
  }
}

extern "C" void kernel_launch(void* const* d_in, const int* in_sizes, int n_in,
                              void* d_out, int out_size, void* d_ws, size_t ws_size,
                              hipStream_t stream) {
  const float* batch = (const float*)d_in[0];
  const float* proj = (const float*)d_in[1];
  float* out = (float*)d_out;
  hipLaunchKernelGGL(prep_proj, dim3(128), dim3(256), 0, stream, proj);
  hipLaunchKernelGGL(transform_kernel, dim3(2, 256), dim3(256), 0, stream, batch);
  hipLaunchKernelGGL(dist_kernel, dim3(8, 8, 8), dim3(256), 0, stream, out);
}